// Round 1
// baseline (1924.806 us; speedup 1.0000x reference)
//
#include <hip/hip_runtime.h>
#include <cstdint>
#include <cstddef>

#define T_STEPS 12
#define NNODES  10000
#define NEDGES  320000
#define IN_DIM  64
#define HID     128
#define EMB     64
#define G3      192

// ---------------------------------------------------------------- setup / CSR
__global__ void k_setup(float* __restrict__ deg, int* __restrict__ cnt, float* __restrict__ hst) {
    int i = blockIdx.x * 256 + threadIdx.x;
    if (i < NNODES) { deg[i] = 1.0f; cnt[i] = 1; }   // self-loop weight 1, count 1
    if (i < NNODES * EMB) hst[i] = 0.0f;             // GRU h0 = 0
}

__global__ void k_edge(const int* __restrict__ eidx, const float* __restrict__ ew,
                       float* __restrict__ deg, int* __restrict__ cnt) {
    int e = blockIdx.x * 256 + threadIdx.x;
    if (e >= NEDGES) return;
    int c = eidx[NEDGES + e];          // col
    atomicAdd(&deg[c], ew[e]);
    atomicAdd(&cnt[c], 1);
}

__global__ void k_dinv(const float* __restrict__ deg, float* __restrict__ dinv) {
    int i = blockIdx.x * 256 + threadIdx.x;
    if (i >= NNODES) return;
    float d = deg[i];
    dinv[i] = (d > 0.0f) ? rsqrtf(d) : 0.0f;
}

__global__ __launch_bounds__(1024) void k_scan(const int* __restrict__ cnt,
                                               int* __restrict__ offs, int* __restrict__ cursor) {
    __shared__ int sh[1024];
    int t = threadIdx.x;
    int loc[10];
    int run = 0;
#pragma unroll
    for (int i = 0; i < 10; ++i) {
        int idx = t * 10 + i;
        int v = (idx < NNODES) ? cnt[idx] : 0;
        loc[i] = run;                   // local exclusive prefix
        run += v;
    }
    sh[t] = run;
    __syncthreads();
    for (int off = 1; off < 1024; off <<= 1) {
        int v = 0;
        if (t >= off) v = sh[t - off];
        __syncthreads();
        if (t >= off) sh[t] += v;
        __syncthreads();
    }
    int base = (t > 0) ? sh[t - 1] : 0;
#pragma unroll
    for (int i = 0; i < 10; ++i) {
        int idx = t * 10 + i;
        if (idx < NNODES) {
            int e = base + loc[i];
            offs[idx] = e;
            cursor[idx] = e;
        }
    }
    if (t == 1023) offs[NNODES] = sh[1023];   // = NEDGES + NNODES
}

__global__ void k_scatter(const int* __restrict__ eidx, const float* __restrict__ ew,
                          const float* __restrict__ dinv, int* __restrict__ cursor,
                          int* __restrict__ srcb, float* __restrict__ wnb) {
    int e = blockIdx.x * 256 + threadIdx.x;
    if (e < NEDGES) {
        int r = eidx[e];
        int c = eidx[NEDGES + e];
        float w = dinv[r] * ew[e] * dinv[c];
        int p = atomicAdd(&cursor[c], 1);
        srcb[p] = r; wnb[p] = w;
    } else if (e < NEDGES + NNODES) {
        int i = e - NEDGES;
        float di = dinv[i];
        int p = atomicAdd(&cursor[i], 1);
        srcb[p] = i; wnb[p] = di * di;
    }
}

// ---------------------------------------------------------------- small GEMM
// C[M,NO] = A[M,K] @ B + optional bias. BT=true: B stored [K,NO] row-major.
// BT=false: B stored [NO,K] row-major (i.e. computes A @ B^T).
template <int K, int NO, int GR, int RPT, bool BT, bool BIAS>
__global__ __launch_bounds__(NO* GR) void k_mm(const float* __restrict__ A,
                                               const float* __restrict__ B,
                                               const float* __restrict__ bias,
                                               float* __restrict__ C, int M) {
    constexpr int NOP = NO + 1;
    __shared__ float Bs[K * NOP];   // [k][c], padded row -> conflict-free
    const int tid = threadIdx.x;
    constexpr int NTHR = NO * GR;
    for (int i = tid; i < K * NO; i += NTHR) {
        if (BT) { int k = i / NO, c = i - k * NO; Bs[k * NOP + c] = B[i]; }
        else    { int c = i / K,  k = i - c * K;  Bs[k * NOP + c] = B[i]; }
    }
    __syncthreads();
    const int c  = tid % NO;
    const int rg = tid / NO;
    const float bv = BIAS ? bias[c] : 0.0f;
    for (int r0 = (blockIdx.x * GR + rg) * RPT; r0 < M; r0 += gridDim.x * GR * RPT) {
        int r0u = __builtin_amdgcn_readfirstlane(r0);
        float acc[RPT];
#pragma unroll
        for (int i = 0; i < RPT; ++i) acc[i] = bv;
        const float4* A4 = (const float4*)A + (size_t)r0u * (K / 4);
        for (int k0 = 0; k0 < K; k0 += 4) {
            float a[RPT][4];
#pragma unroll
            for (int i = 0; i < RPT; ++i) {
                float4 v = A4[i * (K / 4) + (k0 >> 2)];
                a[i][0] = v.x; a[i][1] = v.y; a[i][2] = v.z; a[i][3] = v.w;
            }
#pragma unroll
            for (int j = 0; j < 4; ++j) {
                float b = Bs[(k0 + j) * NOP + c];
#pragma unroll
                for (int i = 0; i < RPT; ++i) acc[i] = fmaf(a[i][j], b, acc[i]);
            }
        }
#pragma unroll
        for (int i = 0; i < RPT; ++i) C[(size_t)(r0 + i) * NO + c] = acc[i];
    }
}

// ---------------------------------------------------------------- aggregation
// One wave per (t,node): out[t,node,:] = bias + sum_e w[e]*H[t,src[e],:], opt relu.
template <int F, bool RELU>
__global__ __launch_bounds__(256) void k_agg(const float* __restrict__ H,
                                             const int* __restrict__ srcb,
                                             const float* __restrict__ wnb,
                                             const int* __restrict__ offs,
                                             const float* __restrict__ bias,
                                             float* __restrict__ out) {
    int wid = (blockIdx.x * 256 + threadIdx.x) >> 6;
    wid = __builtin_amdgcn_readfirstlane(wid);
    if (wid >= T_STEPS * NNODES) return;
    int lane = threadIdx.x & 63;
    int t    = wid / NNODES;
    int node = wid - t * NNODES;
    int beg = offs[node], end = offs[node + 1];
    const float* Ht = H + (size_t)t * NNODES * F;
    if (F == 128) {
        const float2* H2 = (const float2*)Ht;
        float2 acc = ((const float2*)bias)[lane];
        for (int e = beg; e < end; ++e) {
            int s = srcb[e];
            float w = wnb[e];
            float2 v = H2[(size_t)s * 64 + lane];
            acc.x = fmaf(w, v.x, acc.x);
            acc.y = fmaf(w, v.y, acc.y);
        }
        if (RELU) { acc.x = fmaxf(acc.x, 0.0f); acc.y = fmaxf(acc.y, 0.0f); }
        ((float2*)out)[(size_t)wid * 64 + lane] = acc;
    } else {
        float acc = bias[lane];
        for (int e = beg; e < end; ++e) {
            int s = srcb[e];
            float w = wnb[e];
            acc = fmaf(w, Ht[(size_t)s * F + lane], acc);
        }
        if (RELU) acc = fmaxf(acc, 0.0f);
        out[(size_t)wid * F + lane] = acc;
    }
}

// ---------------------------------------------------------------- GRU step (gh GEMM + gate fused)
__global__ __launch_bounds__(192) void k_gruh(const float* __restrict__ gi,   // [N,192] for this t
                                              const float* __restrict__ W_hh, // [192,64]
                                              const float* __restrict__ b_hh,
                                              float* __restrict__ h) {        // [N,64] in/out
    constexpr int KP = 65;
    __shared__ float Wh[G3 * KP];      // [c][k] padded
    __shared__ float ghs[8][G3 + 1];
    int tid = threadIdx.x;
    for (int i = tid; i < G3 * 64; i += 192) {
        int c = i >> 6, k = i & 63;
        Wh[c * KP + k] = W_hh[i];
    }
    __syncthreads();
    float bh = b_hh[tid];
    for (int it = 0; it < 5; ++it) {
        int r0 = (blockIdx.x * 5 + it) * 8;          // 250 blocks * 5 * 8 = 10000 rows
        int r0u = __builtin_amdgcn_readfirstlane(r0);
        float acc[8];
#pragma unroll
        for (int i = 0; i < 8; ++i) acc[i] = bh;
        const float4* H4 = (const float4*)h + (size_t)r0u * 16;
        for (int k0 = 0; k0 < 64; k0 += 4) {
            float a[8][4];
#pragma unroll
            for (int i = 0; i < 8; ++i) {
                float4 v = H4[i * 16 + (k0 >> 2)];
                a[i][0] = v.x; a[i][1] = v.y; a[i][2] = v.z; a[i][3] = v.w;
            }
#pragma unroll
            for (int j = 0; j < 4; ++j) {
                float w = Wh[tid * KP + k0 + j];
#pragma unroll
                for (int i = 0; i < 8; ++i) acc[i] = fmaf(a[i][j], w, acc[i]);
            }
        }
#pragma unroll
        for (int i = 0; i < 8; ++i) ghs[i][tid] = acc[i];
        __syncthreads();
        for (int item = tid; item < 512; item += 192) {
            int rr = item >> 6, f = item & 63;
            int grow = r0 + rr;
            const float* gir = gi + (size_t)grow * G3;
            float ir = gir[f], iz = gir[64 + f], inn = gir[128 + f];
            float hr = ghs[rr][f], hz = ghs[rr][64 + f], hn = ghs[rr][128 + f];
            float rg = 1.0f / (1.0f + expf(-(ir + hr)));
            float zg = 1.0f / (1.0f + expf(-(iz + hz)));
            float ng = tanhf(fmaf(rg, hn, inn));
            float hp = h[(size_t)grow * 64 + f];
            h[(size_t)grow * 64 + f] = fmaf(zg, hp - ng, ng);   // (1-z)*n + z*h
        }
        __syncthreads();
    }
}

__global__ void k_zcopy(const float* __restrict__ h, float* __restrict__ out) {
    int i = blockIdx.x * 256 + threadIdx.x;
    if (i < NNODES * EMB) out[(size_t)NNODES * NNODES + i] = h[i];
}

// ---------------------------------------------------------------- decoder
__device__ __forceinline__ float softplusf(float x) {
    return fmaxf(x, 0.0f) + log1pf(expf(-fabsf(x)));
}

__global__ __launch_bounds__(256) void k_dec(const float* __restrict__ z,
                                             const float* __restrict__ dbias,
                                             float* __restrict__ out) {
    constexpr int SP = 128;
    __shared__ float Zr[64 * SP];   // [k][r]
    __shared__ float Zc[64 * SP];   // [k][c]
    int tid = threadIdx.x;
    int r0 = blockIdx.y * 128, c0 = blockIdx.x * 128;
    const float4* z4 = (const float4*)z;
    for (int idx = tid; idx < 2048; idx += 256) {
        int rowl = idx & 127;          // lanes along rows -> conflict-free LDS stores
        int k4   = idx >> 7;           // 0..15
        int gr = r0 + rowl, gc = c0 + rowl;
        float4 v = (gr < NNODES) ? z4[(size_t)gr * 16 + k4] : make_float4(0.f, 0.f, 0.f, 0.f);
        float4 u = (gc < NNODES) ? z4[(size_t)gc * 16 + k4] : make_float4(0.f, 0.f, 0.f, 0.f);
        int kb = k4 * 4;
        Zr[(kb + 0) * SP + rowl] = v.x; Zr[(kb + 1) * SP + rowl] = v.y;
        Zr[(kb + 2) * SP + rowl] = v.z; Zr[(kb + 3) * SP + rowl] = v.w;
        Zc[(kb + 0) * SP + rowl] = u.x; Zc[(kb + 1) * SP + rowl] = u.y;
        Zc[(kb + 2) * SP + rowl] = u.z; Zc[(kb + 3) * SP + rowl] = u.w;
    }
    __syncthreads();
    int tx = tid & 15, ty = tid >> 4;
    float acc[8][8];
#pragma unroll
    for (int i = 0; i < 8; ++i)
#pragma unroll
        for (int j = 0; j < 8; ++j) acc[i][j] = 0.0f;
    for (int k = 0; k < 64; ++k) {
        float a[8], b[8];
        *(float4*)(a)     = *(const float4*)&Zr[k * SP + ty * 8];
        *(float4*)(a + 4) = *(const float4*)&Zr[k * SP + ty * 8 + 4];
        *(float4*)(b)     = *(const float4*)&Zc[k * SP + tx * 8];
        *(float4*)(b + 4) = *(const float4*)&Zc[k * SP + tx * 8 + 4];
#pragma unroll
        for (int i = 0; i < 8; ++i)
#pragma unroll
            for (int j = 0; j < 8; ++j) acc[i][j] = fmaf(a[i], b[j], acc[i][j]);
    }
    float db = dbias[0];
    bool full = (r0 + 128 <= NNODES) && (c0 + 128 <= NNODES);
    if (full) {
#pragma unroll
        for (int i = 0; i < 8; ++i) {
            size_t ro = (size_t)(r0 + ty * 8 + i) * NNODES + (c0 + tx * 8);
            float4 o0, o1;
            o0.x = softplusf(acc[i][0] + db); o0.y = softplusf(acc[i][1] + db);
            o0.z = softplusf(acc[i][2] + db); o0.w = softplusf(acc[i][3] + db);
            o1.x = softplusf(acc[i][4] + db); o1.y = softplusf(acc[i][5] + db);
            o1.z = softplusf(acc[i][6] + db); o1.w = softplusf(acc[i][7] + db);
            *(float4*)(out + ro)     = o0;
            *(float4*)(out + ro + 4) = o1;
        }
    } else {
        for (int i = 0; i < 8; ++i) {
            int gr = r0 + ty * 8 + i;
            if (gr >= NNODES) continue;
            for (int j = 0; j < 8; ++j) {
                int gc = c0 + tx * 8 + j;
                if (gc >= NNODES) continue;
                out[(size_t)gr * NNODES + gc] = softplusf(acc[i][j] + db);
            }
        }
    }
}

// ---------------------------------------------------------------- launch
extern "C" void kernel_launch(void* const* d_in, const int* in_sizes, int n_in,
                              void* d_out, int out_size, void* d_ws, size_t ws_size,
                              hipStream_t stream) {
    const float* x_seq = (const float*)d_in[0];
    const int*   eidx  = (const int*)d_in[1];
    const float* ew    = (const float*)d_in[2];
    const float* W1    = (const float*)d_in[3];
    const float* b1    = (const float*)d_in[4];
    const float* W2    = (const float*)d_in[5];
    const float* b2    = (const float*)d_in[6];
    const float* W_ih  = (const float*)d_in[7];
    const float* W_hh  = (const float*)d_in[8];
    const float* b_ih  = (const float*)d_in[9];
    const float* b_hh  = (const float*)d_in[10];
    const float* dbias = (const float*)d_in[11];
    float* out = (float*)d_out;

    char* wsp = (char*)d_ws;
    auto alloc = [&](size_t bytes) {
        char* p = wsp;
        wsp += (bytes + 255) & ~(size_t)255;
        return p;
    };
    float* deg    = (float*)alloc((size_t)NNODES * 4);
    float* dinv   = (float*)alloc((size_t)NNODES * 4);
    int*   cnt    = (int*)alloc((size_t)NNODES * 4);
    int*   offs   = (int*)alloc((size_t)(NNODES + 1) * 4);
    int*   cursor = (int*)alloc((size_t)NNODES * 4);
    int*   srcb   = (int*)alloc((size_t)(NEDGES + NNODES) * 4);
    float* wnb    = (float*)alloc((size_t)(NEDGES + NNODES) * 4);
    float* hst    = (float*)alloc((size_t)NNODES * EMB * 4);
    float* Buf1   = (float*)alloc((size_t)T_STEPS * NNODES * G3 * 4);   // 92.2 MB (also holds [12N,128])
    float* Buf2   = (float*)alloc((size_t)T_STEPS * NNODES * HID * 4);  // 61.4 MB

    const int M = T_STEPS * NNODES;   // 120000

    k_setup<<<(NNODES * EMB + 255) / 256, 256, 0, stream>>>(deg, cnt, hst);
    k_edge<<<(NEDGES + 255) / 256, 256, 0, stream>>>(eidx, ew, deg, cnt);
    k_dinv<<<(NNODES + 255) / 256, 256, 0, stream>>>(deg, dinv);
    k_scan<<<1, 1024, 0, stream>>>(cnt, offs, cursor);
    k_scatter<<<(NEDGES + NNODES + 255) / 256, 256, 0, stream>>>(eidx, ew, dinv, cursor, srcb, wnb);

    // GCN layer 1 (batched over T): Buf1 = x@W1 ; Buf2 = relu(agg(Buf1)+b1)
    k_mm<64, 128, 2, 8, true, false><<<1024, 256, 0, stream>>>(x_seq, W1, nullptr, Buf1, M);
    k_agg<128, true><<<M / 4, 256, 0, stream>>>(Buf1, srcb, wnb, offs, b1, Buf2);
    // GCN layer 2: Buf1 = Buf2@W2 ; Buf2 = agg(Buf1)+b2  (= z_seq [12N,64])
    k_mm<128, 64, 4, 8, true, false><<<1024, 256, 0, stream>>>(Buf2, W2, nullptr, Buf1, M);
    k_agg<64, false><<<M / 4, 256, 0, stream>>>(Buf1, srcb, wnb, offs, b2, Buf2);
    // GRU input gates for ALL t in one GEMM: Buf1 = z_seq @ W_ih^T + b_ih  [12N,192]
    k_mm<64, 192, 1, 8, false, true><<<1024, 192, 0, stream>>>(Buf2, W_ih, b_ih, Buf1, M);
    // Sequential GRU: h updated in place, 12 steps
    for (int t = 0; t < T_STEPS; ++t) {
        k_gruh<<<250, 192, 0, stream>>>(Buf1 + (size_t)t * NNODES * G3, W_hh, b_hh, hst);
    }
    k_zcopy<<<(NNODES * EMB + 255) / 256, 256, 0, stream>>>(hst, out);
    dim3 gdec((NNODES + 127) / 128, (NNODES + 127) / 128);
    k_dec<<<gdec, 256, 0, stream>>>(hst, dbias, out);
}

// Round 2
// 1911.464 us; speedup vs baseline: 1.0070x; 1.0070x over previous
//
#include <hip/hip_runtime.h>
#include <cstdint>
#include <cstddef>

#define T_STEPS 12
#define NNODES  10000
#define NEDGES  320000
#define IN_DIM  64
#define HID     128
#define EMB     64
#define G3      192
#define NPAD    10112   // 79*128, decoder tile padding

typedef __attribute__((ext_vector_type(8))) short short8;
typedef __attribute__((ext_vector_type(4))) float f32x4;

// ---------------------------------------------------------------- setup / CSR
__global__ void k_setup(float* __restrict__ deg, int* __restrict__ cnt) {
    int i = blockIdx.x * 256 + threadIdx.x;
    if (i < NNODES) { deg[i] = 1.0f; cnt[i] = 1; }   // self-loop weight 1, count 1
}

__global__ void k_edge(const int* __restrict__ eidx, const float* __restrict__ ew,
                       float* __restrict__ deg, int* __restrict__ cnt) {
    int e = blockIdx.x * 256 + threadIdx.x;
    if (e >= NEDGES) return;
    int c = eidx[NEDGES + e];          // col
    atomicAdd(&deg[c], ew[e]);
    atomicAdd(&cnt[c], 1);
}

__global__ void k_dinv(const float* __restrict__ deg, float* __restrict__ dinv) {
    int i = blockIdx.x * 256 + threadIdx.x;
    if (i >= NNODES) return;
    float d = deg[i];
    dinv[i] = (d > 0.0f) ? rsqrtf(d) : 0.0f;
}

__global__ __launch_bounds__(1024) void k_scan(const int* __restrict__ cnt,
                                               int* __restrict__ offs, int* __restrict__ cursor) {
    __shared__ int sh[1024];
    int t = threadIdx.x;
    int loc[10];
    int run = 0;
#pragma unroll
    for (int i = 0; i < 10; ++i) {
        int idx = t * 10 + i;
        int v = (idx < NNODES) ? cnt[idx] : 0;
        loc[i] = run;
        run += v;
    }
    sh[t] = run;
    __syncthreads();
    for (int off = 1; off < 1024; off <<= 1) {
        int v = 0;
        if (t >= off) v = sh[t - off];
        __syncthreads();
        if (t >= off) sh[t] += v;
        __syncthreads();
    }
    int base = (t > 0) ? sh[t - 1] : 0;
#pragma unroll
    for (int i = 0; i < 10; ++i) {
        int idx = t * 10 + i;
        if (idx < NNODES) {
            int e = base + loc[i];
            offs[idx] = e;
            cursor[idx] = e;
        }
    }
    if (t == 1023) offs[NNODES] = sh[1023];
}

__global__ void k_scatter(const int* __restrict__ eidx, const float* __restrict__ ew,
                          const float* __restrict__ dinv, int* __restrict__ cursor,
                          int* __restrict__ srcb, float* __restrict__ wnb) {
    int e = blockIdx.x * 256 + threadIdx.x;
    if (e < NEDGES) {
        int r = eidx[e];
        int c = eidx[NEDGES + e];
        float w = dinv[r] * ew[e] * dinv[c];
        int p = atomicAdd(&cursor[c], 1);
        srcb[p] = r; wnb[p] = w;
    } else if (e < NEDGES + NNODES) {
        int i = e - NEDGES;
        float di = dinv[i];
        int p = atomicAdd(&cursor[i], 1);
        srcb[p] = i; wnb[p] = di * di;
    }
}

// ---------------------------------------------------------------- small GEMM
// C[M,NO] = A[M,K] @ B + optional bias. BT=true: B stored [K,NO] row-major.
// BT=false: B stored [NO,K] (computes A @ B^T). PERM: output row r -> (r%N)*12 + r/N.
template <int K, int NO, int GR, int RPT, bool BT, bool BIAS, bool PERM>
__global__ __launch_bounds__(NO* GR) void k_mm(const float* __restrict__ A,
                                               const float* __restrict__ B,
                                               const float* __restrict__ bias,
                                               float* __restrict__ C, int M) {
    constexpr int NOP = NO + 1;
    __shared__ float Bs[K * NOP];   // [k][c]
    const int tid = threadIdx.x;
    constexpr int NTHR = NO * GR;
    for (int i = tid; i < K * NO; i += NTHR) {
        if (BT) { int k = i / NO, c = i - k * NO; Bs[k * NOP + c] = B[i]; }
        else    { int c = i / K,  k = i - c * K;  Bs[k * NOP + c] = B[i]; }
    }
    __syncthreads();
    const int c  = tid % NO;
    const int rg = tid / NO;
    const float bv = BIAS ? bias[c] : 0.0f;
    for (int r0 = (blockIdx.x * GR + rg) * RPT; r0 < M; r0 += gridDim.x * GR * RPT) {
        int r0u = __builtin_amdgcn_readfirstlane(r0);
        float acc[RPT];
#pragma unroll
        for (int i = 0; i < RPT; ++i) acc[i] = bv;
        const float4* A4 = (const float4*)A + (size_t)r0u * (K / 4);
        for (int k0 = 0; k0 < K; k0 += 4) {
            float a[RPT][4];
#pragma unroll
            for (int i = 0; i < RPT; ++i) {
                float4 v = A4[i * (K / 4) + (k0 >> 2)];
                a[i][0] = v.x; a[i][1] = v.y; a[i][2] = v.z; a[i][3] = v.w;
            }
#pragma unroll
            for (int j = 0; j < 4; ++j) {
                float b = Bs[(k0 + j) * NOP + c];
#pragma unroll
                for (int i = 0; i < RPT; ++i) acc[i] = fmaf(a[i][j], b, acc[i]);
            }
        }
#pragma unroll
        for (int i = 0; i < RPT; ++i) {
            int rr = r0 + i;
            size_t orow = PERM ? ((size_t)(rr % NNODES) * T_STEPS + rr / NNODES) : (size_t)rr;
            C[orow * NO + c] = acc[i];
        }
    }
}

// ---------------------------------------------------------------- aggregation
// Node-major layout: H rows are [node][t][F]. One wave per node, all 12 t at once.
template <int F, bool RELU>
__global__ __launch_bounds__(256) void k_agg(const float* __restrict__ H,
                                             const int* __restrict__ srcb,
                                             const float* __restrict__ wnb,
                                             const int* __restrict__ offs,
                                             const float* __restrict__ bias,
                                             float* __restrict__ out) {
    int node = (blockIdx.x * 256 + threadIdx.x) >> 6;
    node = __builtin_amdgcn_readfirstlane(node);
    if (node >= NNODES) return;
    int lane = threadIdx.x & 63;
    int beg = offs[node], end = offs[node + 1];
    if (F == 128) {
        const float2* H2 = (const float2*)H;
        float2 bv = ((const float2*)bias)[lane];
        float2 acc[T_STEPS];
#pragma unroll
        for (int t = 0; t < T_STEPS; ++t) acc[t] = bv;
        for (int e0 = beg; e0 < end; e0 += 64) {
            int idx = e0 + lane;
            int sv = (idx < end) ? srcb[idx] : 0;
            float wv = (idx < end) ? wnb[idx] : 0.0f;
            int m = min(64, end - e0);
            for (int j = 0; j < m; ++j) {
                int sj = __shfl(sv, j);
                float wj = __shfl(wv, j);
                size_t base = (size_t)sj * (T_STEPS * 64);
#pragma unroll
                for (int t = 0; t < T_STEPS; ++t) {
                    float2 hv = H2[base + t * 64 + lane];
                    acc[t].x = fmaf(wj, hv.x, acc[t].x);
                    acc[t].y = fmaf(wj, hv.y, acc[t].y);
                }
            }
        }
        float2* O2 = (float2*)out;
#pragma unroll
        for (int t = 0; t < T_STEPS; ++t) {
            float2 a = acc[t];
            if (RELU) { a.x = fmaxf(a.x, 0.0f); a.y = fmaxf(a.y, 0.0f); }
            O2[((size_t)node * T_STEPS + t) * 64 + lane] = a;
        }
    } else {
        float bv = bias[lane];
        float acc[T_STEPS];
#pragma unroll
        for (int t = 0; t < T_STEPS; ++t) acc[t] = bv;
        for (int e0 = beg; e0 < end; e0 += 64) {
            int idx = e0 + lane;
            int sv = (idx < end) ? srcb[idx] : 0;
            float wv = (idx < end) ? wnb[idx] : 0.0f;
            int m = min(64, end - e0);
            for (int j = 0; j < m; ++j) {
                int sj = __shfl(sv, j);
                float wj = __shfl(wv, j);
                size_t base = (size_t)sj * (T_STEPS * 64);
#pragma unroll
                for (int t = 0; t < T_STEPS; ++t) {
                    acc[t] = fmaf(wj, H[base + t * 64 + lane], acc[t]);
                }
            }
        }
#pragma unroll
        for (int t = 0; t < T_STEPS; ++t) {
            float a = acc[t];
            if (RELU) a = fmaxf(a, 0.0f);
            out[((size_t)node * T_STEPS + t) * 64 + lane] = a;
        }
    }
}

// ---------------------------------------------------------------- fused GRU (all 12 steps)
// gi layout: [node][t][192]. Each block owns 12 rows for the whole sequence; h lives in LDS.
__global__ __launch_bounds__(192) void k_gru(const float* __restrict__ gi,
                                             const float* __restrict__ W_hh,  // [192,64]
                                             const float* __restrict__ b_hh,
                                             float* __restrict__ hout) {      // [N,64]
    constexpr int KP = 65, RPB = 12;
    __shared__ float Wh[G3 * KP];        // [c][k]  49920 B
    __shared__ float ghs[RPB][G3 + 1];   // 9264 B
    __shared__ float hs[RPB][KP];        // 3120 B  -> total 62304 B
    int tid = threadIdx.x;
    for (int i = tid; i < G3 * 64; i += 192) {
        int cc = i >> 6, k = i & 63;
        Wh[cc * KP + k] = W_hh[i];
    }
    for (int i = tid; i < RPB * 64; i += 192) hs[i >> 6][i & 63] = 0.0f;
    __syncthreads();
    int r0 = blockIdx.x * RPB;
    float bh = b_hh[tid];
    for (int t = 0; t < T_STEPS; ++t) {
        float acc[RPB];
#pragma unroll
        for (int i = 0; i < RPB; ++i) acc[i] = bh;
#pragma unroll
        for (int k0 = 0; k0 < 64; k0 += 4) {
            float wv[4];
#pragma unroll
            for (int j = 0; j < 4; ++j) wv[j] = Wh[tid * KP + k0 + j];
#pragma unroll
            for (int i = 0; i < RPB; ++i) {
#pragma unroll
                for (int j = 0; j < 4; ++j) acc[i] = fmaf(hs[i][k0 + j], wv[j], acc[i]);
            }
        }
#pragma unroll
        for (int i = 0; i < RPB; ++i) ghs[i][tid] = acc[i];
        __syncthreads();
        for (int item = tid; item < RPB * 64; item += 192) {
            int rr = item >> 6, f = item & 63;
            int grow = r0 + rr;
            if (grow < NNODES) {
                const float* gir = gi + ((size_t)grow * T_STEPS + t) * G3;
                float ir = gir[f], iz = gir[64 + f], inn = gir[128 + f];
                float hr = ghs[rr][f], hz = ghs[rr][64 + f], hn = ghs[rr][128 + f];
                float rg = 1.0f / (1.0f + expf(-(ir + hr)));
                float zg = 1.0f / (1.0f + expf(-(iz + hz)));
                float ng = tanhf(fmaf(rg, hn, inn));
                float hp = hs[rr][f];
                hs[rr][f] = fmaf(zg, hp - ng, ng);    // (1-z)*n + z*h
            }
        }
        __syncthreads();
    }
    for (int item = tid; item < RPB * 64; item += 192) {
        int rr = item >> 6, f = item & 63;
        int grow = r0 + rr;
        if (grow < NNODES) hout[(size_t)grow * 64 + f] = hs[rr][f];
    }
}

__global__ void k_zcopy(const float* __restrict__ h, float* __restrict__ out) {
    int i = blockIdx.x * 256 + threadIdx.x;
    if (i < NNODES * EMB) out[(size_t)NNODES * NNODES + i] = h[i];
}

// ---------------------------------------------------------------- bf16 hi/lo split
__global__ void k_zsplit(const float* __restrict__ h,
                         unsigned short* __restrict__ zhi, unsigned short* __restrict__ zlo) {
    int i = blockIdx.x * 256 + threadIdx.x;
    if (i >= NPAD * EMB) return;
    float x = (i < NNODES * EMB) ? h[i] : 0.0f;
    uint32_t b = __float_as_uint(x);
    uint32_t rh = (b + 0x7FFFu + ((b >> 16) & 1u)) & 0xFFFF0000u;   // RNE bf16 of x
    float fhi = __uint_as_float(rh);
    float lo = x - fhi;
    uint32_t bl = __float_as_uint(lo);
    uint32_t rl = (bl + 0x7FFFu + ((bl >> 16) & 1u)) & 0xFFFF0000u;
    zhi[i] = (unsigned short)(rh >> 16);
    zlo[i] = (unsigned short)(rl >> 16);
}

// ---------------------------------------------------------------- decoder (MFMA, K=192 hi/lo trick)
__device__ __forceinline__ float softplusf(float x) {
    return fmaxf(x, 0.0f) + log1pf(expf(-fabsf(x)));
}

__global__ __launch_bounds__(256) void k_dec(const unsigned short* __restrict__ zhi,
                                             const unsigned short* __restrict__ zlo,
                                             const float* __restrict__ dbias,
                                             float* __restrict__ out) {
    // LDS: per tile 128 rows x 128 bf16 (hi 64 | lo 64), 16B chunks XOR-swizzled by row&15.
    __shared__ short As[128 * 128];
    __shared__ short Bs[128 * 128];
    int tid = threadIdx.x;
    int r0 = blockIdx.y * 128, c0 = blockIdx.x * 128;
    const float4* zh4 = (const float4*)zhi;
    const float4* zl4 = (const float4*)zlo;
#pragma unroll
    for (int p8 = 0; p8 < 8; ++p8) {
        int idx = p8 * 256 + tid;
        int row = idx >> 4, c = idx & 15;
        float4 va = (c < 8) ? zh4[(size_t)(r0 + row) * 8 + c] : zl4[(size_t)(r0 + row) * 8 + (c - 8)];
        float4 vb = (c < 8) ? zh4[(size_t)(c0 + row) * 8 + c] : zl4[(size_t)(c0 + row) * 8 + (c - 8)];
        int pos = c ^ (row & 15);
        *(float4*)&As[row * 128 + pos * 8] = va;
        *(float4*)&Bs[row * 128 + pos * 8] = vb;
    }
    __syncthreads();
    int lane = tid & 63, w = tid >> 6;
    int r = lane & 15, q = lane >> 4;
    f32x4 acc[2][8];
#pragma unroll
    for (int mt = 0; mt < 2; ++mt)
#pragma unroll
        for (int nt = 0; nt < 8; ++nt) acc[mt][nt] = (f32x4){0.f, 0.f, 0.f, 0.f};
    // K=192: A chunks [hi0,hi1,hi0,hi1,lo0,lo1] ; B chunks [hi0,hi1,lo0,lo1,hi0,hi1]
    const int aSel[6] = {0, 4, 0, 4, 8, 12};
    const int bSel[6] = {0, 4, 8, 12, 0, 4};
#pragma unroll
    for (int ks = 0; ks < 6; ++ks) {
        short8 af[2], bf[8];
#pragma unroll
        for (int mt = 0; mt < 2; ++mt) {
            int rowA = w * 32 + mt * 16 + r;
            af[mt] = *(const short8*)&As[rowA * 128 + ((aSel[ks] + q) ^ r) * 8];
        }
#pragma unroll
        for (int nt = 0; nt < 8; ++nt) {
            int rowB = nt * 16 + r;
            bf[nt] = *(const short8*)&Bs[rowB * 128 + ((bSel[ks] + q) ^ r) * 8];
        }
#pragma unroll
        for (int mt = 0; mt < 2; ++mt)
#pragma unroll
            for (int nt = 0; nt < 8; ++nt)
                acc[mt][nt] = __builtin_amdgcn_mfma_f32_16x16x32_bf16(af[mt], bf[nt], acc[mt][nt], 0, 0, 0);
    }
    float db = dbias[0];
    bool full = (r0 + 128 <= NNODES) && (c0 + 128 <= NNODES);
    if (full) {
#pragma unroll
        for (int mt = 0; mt < 2; ++mt) {
            int rgb = r0 + w * 32 + mt * 16 + q * 4;
#pragma unroll
            for (int nt = 0; nt < 8; ++nt) {
                int cg = c0 + nt * 16 + r;
#pragma unroll
                for (int reg = 0; reg < 4; ++reg)
                    out[(size_t)(rgb + reg) * NNODES + cg] = softplusf(acc[mt][nt][reg] + db);
            }
        }
    } else {
        for (int mt = 0; mt < 2; ++mt) {
            int rgb = r0 + w * 32 + mt * 16 + q * 4;
            for (int nt = 0; nt < 8; ++nt) {
                int cg = c0 + nt * 16 + r;
                if (cg >= NNODES) continue;
                for (int reg = 0; reg < 4; ++reg) {
                    if (rgb + reg < NNODES)
                        out[(size_t)(rgb + reg) * NNODES + cg] = softplusf(acc[mt][nt][reg] + db);
                }
            }
        }
    }
}

// ---------------------------------------------------------------- launch
extern "C" void kernel_launch(void* const* d_in, const int* in_sizes, int n_in,
                              void* d_out, int out_size, void* d_ws, size_t ws_size,
                              hipStream_t stream) {
    const float* x_seq = (const float*)d_in[0];
    const int*   eidx  = (const int*)d_in[1];
    const float* ew    = (const float*)d_in[2];
    const float* W1    = (const float*)d_in[3];
    const float* b1    = (const float*)d_in[4];
    const float* W2    = (const float*)d_in[5];
    const float* b2    = (const float*)d_in[6];
    const float* W_ih  = (const float*)d_in[7];
    const float* W_hh  = (const float*)d_in[8];
    const float* b_ih  = (const float*)d_in[9];
    const float* b_hh  = (const float*)d_in[10];
    const float* dbias = (const float*)d_in[11];
    float* out = (float*)d_out;

    char* wsp = (char*)d_ws;
    auto alloc = [&](size_t bytes) {
        char* p = wsp;
        wsp += (bytes + 255) & ~(size_t)255;
        return p;
    };
    float* deg    = (float*)alloc((size_t)NNODES * 4);
    float* dinv   = (float*)alloc((size_t)NNODES * 4);
    int*   cnt    = (int*)alloc((size_t)NNODES * 4);
    int*   offs   = (int*)alloc((size_t)(NNODES + 1) * 4);
    int*   cursor = (int*)alloc((size_t)NNODES * 4);
    int*   srcb   = (int*)alloc((size_t)(NEDGES + NNODES) * 4);
    float* wnb    = (float*)alloc((size_t)(NEDGES + NNODES) * 4);
    float* hst    = (float*)alloc((size_t)NNODES * EMB * 4);
    unsigned short* zhi = (unsigned short*)alloc((size_t)NPAD * EMB * 2);
    unsigned short* zlo = (unsigned short*)alloc((size_t)NPAD * EMB * 2);
    float* Buf1   = (float*)alloc((size_t)T_STEPS * NNODES * G3 * 4);   // 92.2 MB
    float* Buf2   = (float*)alloc((size_t)T_STEPS * NNODES * HID * 4);  // 61.4 MB

    const int M = T_STEPS * NNODES;   // 120000

    k_setup<<<(NNODES + 255) / 256, 256, 0, stream>>>(deg, cnt);
    k_edge<<<(NEDGES + 255) / 256, 256, 0, stream>>>(eidx, ew, deg, cnt);
    k_dinv<<<(NNODES + 255) / 256, 256, 0, stream>>>(deg, dinv);
    k_scan<<<1, 1024, 0, stream>>>(cnt, offs, cursor);
    k_scatter<<<(NEDGES + NNODES + 255) / 256, 256, 0, stream>>>(eidx, ew, dinv, cursor, srcb, wnb);

    // GCN layer 1: Buf1 = x@W1 (rows permuted to [n][t]); Buf2 = relu(agg(Buf1)+b1)
    k_mm<64, 128, 2, 8, true, false, true><<<1024, 256, 0, stream>>>(x_seq, W1, nullptr, Buf1, M);
    k_agg<128, true><<<(NNODES * 64 + 255) / 256, 256, 0, stream>>>(Buf1, srcb, wnb, offs, b1, Buf2);
    // GCN layer 2: Buf1 = Buf2@W2 ; Buf2 = agg(Buf1)+b2  (= z_seq, [n][t][64])
    k_mm<128, 64, 4, 8, true, false, false><<<1024, 256, 0, stream>>>(Buf2, W2, nullptr, Buf1, M);
    k_agg<64, false><<<(NNODES * 64 + 255) / 256, 256, 0, stream>>>(Buf1, srcb, wnb, offs, b2, Buf2);
    // GRU input gates for all t: Buf1 = z_seq @ W_ih^T + b_ih  [n][t][192]
    k_mm<64, 192, 1, 8, false, true, false><<<1024, 192, 0, stream>>>(Buf2, W_ih, b_ih, Buf1, M);
    // Fused 12-step GRU, h resident in LDS
    k_gru<<<(NNODES + 11) / 12, 192, 0, stream>>>(Buf1, W_hh, b_hh, hst);
    k_zcopy<<<(NNODES * EMB + 255) / 256, 256, 0, stream>>>(hst, out);
    k_zsplit<<<(NPAD * EMB + 255) / 256, 256, 0, stream>>>(hst, zhi, zlo);
    dim3 gdec(NPAD / 128, NPAD / 128);
    k_dec<<<gdec, 256, 0, stream>>>(zhi, zlo, dbias, out);
}